// Round 5
// baseline (1767.591 us; speedup 1.0000x reference)
//
#include <hip/hip_runtime.h>
#include <hip/hip_bf16.h>

#define BATCH 256
#define SEQ   250
#define HID   512
#define INDIM 5

#define NBLK  64   // 8 batch groups x 8 hidden tiles
#define MB    32   // batch rows per block
#define HB    64   // hidden units per block (8 members per group)

typedef __attribute__((ext_vector_type(8))) short short8;
typedef __attribute__((ext_vector_type(4))) float f32x4;
typedef __attribute__((ext_vector_type(4))) unsigned int u32x4;

__device__ __forceinline__ float sigmoidf_fast(float x) {
  return 1.0f / (1.0f + __expf(-x));
}
__device__ __forceinline__ float tanhf_fast(float x) {
  return 2.0f / (1.0f + __expf(-2.0f * x)) - 1.0f;
}
__device__ __forceinline__ unsigned short f2bf_rne(float x) {
  union { float f; unsigned u; } v; v.f = x;
  unsigned r = v.u + 0x7fffu + ((v.u >> 16) & 1u);
  return (unsigned short)(r >> 16);
}
__device__ __forceinline__ float bf2f(unsigned short h) {
  union { unsigned u; float f; } v; v.u = ((unsigned)h) << 16;
  return v.f;
}

// Cache-bypassing (sc0 sc1 -> MALL, same path as agent-scope relaxed
// atomics) 16B load; batched, one waitcnt.
__device__ __forceinline__ void mall_load_16B(u32x4& dst, const void* ptr) {
  asm volatile("global_load_dwordx4 %0, %1, off sc0 sc1"
               : "=v"(dst) : "v"(ptr) : "memory");
}
__device__ __forceinline__ void vm_drain() {
  asm volatile("s_waitcnt vmcnt(0)" ::: "memory");
}

// Persistent LSTM, fence-free MALL exchange (R3), group fan-in reduced
// 32 -> 8 by fat blocks (1024 thr, HB=64). All 8 member flags of a group
// live in ONE 64B line -> one-load poll. 16 waves: wave w = (gate g = w&3,
// hidden subtile s = w>>2).
__global__ __launch_bounds__(1024, 4) void lstm_persist(
    const float* __restrict__ strokes, const float* __restrict__ W_ih,
    const float* __restrict__ W_hh, const float* __restrict__ b_ih,
    const float* __restrict__ b_hh, const float* __restrict__ W_out,
    const float* __restrict__ b_out, float* __restrict__ out,
    unsigned short* __restrict__ hbuf,   // 2 * 256 * 512 bf16 (double buffer)
    int* __restrict__ flags)             // 8 groups * 16 ints (64B per group)
{
  const int tid  = threadIdx.x;
  const int bid  = blockIdx.x;
  const int bt   = bid & 7;      // batch group
  const int ht   = bid >> 3;     // hidden tile 0..7 (64 cols each)
  const int wv   = tid >> 6;     // wave 0..15
  const int g    = wv & 3;       // gate type (i,f,g,o)
  const int s    = wv >> 2;      // hidden subtile 0..3 within block
  const int lane = tid & 63;
  const int n16  = lane & 15;
  const int q    = lane >> 4;

  __shared__ u32x4 h_lds[MB * 64];                // 32 KB, swizzled 16B chunks
  __shared__ float g_lds[4][MB][68];              // gates, stride 68 (2-way free)
  __shared__ float wih_lds[4][HB][INDIM];
  __shared__ float bias_lds[4][HB];

  // ---- preload W_ih slice + combined biases into LDS (256 lanes)
  if (tid < 256) {
    int gg = tid >> 6, j = tid & 63;
    int r = gg * HID + ht * HB + j;
    #pragma unroll
    for (int i = 0; i < INDIM; ++i) wih_lds[gg][j][i] = W_ih[r * INDIM + i];
    bias_lds[gg][j] = b_ih[r] + b_hh[r];
  }

  // ---- preload W_hh as bf16 MFMA B-fragments (weight-stationary)
  // wave (g,s) holds gate rows r = g*512 + ht*64 + s*16 + n16
  short8 wfrag[16];
  {
    const float* wr = W_hh + (size_t)(g * HID + ht * HB + s * 16 + n16) * HID;
    #pragma unroll
    for (int kb = 0; kb < 16; ++kb) {
      const float* p = wr + kb * 32 + q * 8;
      short8 f;
      #pragma unroll
      for (int j = 0; j < 8; ++j) f[j] = (short)f2bf_rne(p[j]);
      wfrag[kb] = f;
    }
  }
  __syncthreads();

  // activation-phase mapping: thread -> (batch row am, hidden pair aj)
  const int am = tid >> 5;            // 0..31
  const int aj = (tid & 31) * 2;      // 0,2,..,62
  const int ab = bt * MB + am;        // global batch row
  float c0 = 0.f, c1 = 0.f;

  unsigned short* hb0 = hbuf;
  unsigned short* hb1 = hbuf + BATCH * HID;

  for (int t = 0; t < SEQ; ++t) {
    unsigned short* hprev = (t & 1) ? hb0 : hb1;
    unsigned short* hcur  = (t & 1) ? hb1 : hb0;

    const float* sp = strokes + ((size_t)ab * SEQ + t) * INDIM;
    float s0 = sp[0], s1 = sp[1], s2 = sp[2], s3 = sp[3], s4 = sp[4];

    f32x4 acc[2][2] = {};
    if (t > 0) {
      // ---- stage h(t-1) tile (32 rows x 512 bf16 = 32 KB) into LDS.
      // 2 x 16B per thread (2048 chunks / 1024 threads), one MALL round trip.
      const char* hsrc = reinterpret_cast<const char*>(hprev + (size_t)bt * MB * HID);
      u32x4 tmp[2];
      #pragma unroll
      for (int i = 0; i < 2; ++i) {
        mall_load_16B(tmp[i], hsrc + (size_t)(i * 1024 + tid) * 16);
      }
      vm_drain();
      #pragma unroll
      for (int i = 0; i < 2; ++i) {
        int off = i * 1024 + tid;
        int row = off >> 6;
        int c   = off & 63;
        h_lds[row * 64 + (c ^ (row & 7))] = tmp[i];
      }
      __syncthreads();

      #pragma unroll
      for (int kb = 0; kb < 16; ++kb) {
        #pragma unroll
        for (int mt = 0; mt < 2; ++mt) {
          const int row = mt * 16 + n16;
          const int c   = kb * 4 + q;                 // 16B chunk in row
          const short8 a = *reinterpret_cast<const short8*>(
              &h_lds[row * 64 + (c ^ (row & 7))]);
          acc[mt][kb & 1] = __builtin_amdgcn_mfma_f32_16x16x32_bf16(
              a, wfrag[kb], acc[mt][kb & 1], 0, 0, 0);
        }
      }
    }

    // C-layout: batch row = q*4 + reg, hidden col (in block) = s*16 + n16
    #pragma unroll
    for (int mt = 0; mt < 2; ++mt) {
      #pragma unroll
      for (int r = 0; r < 4; ++r) {
        g_lds[g][mt * 16 + q * 4 + r][s * 16 + n16] = acc[mt][0][r] + acc[mt][1][r];
      }
    }
    __syncthreads();

    float hv[2];
    #pragma unroll
    for (int e = 0; e < 2; ++e) {
      int j = aj + e;
      float pre[4];
      #pragma unroll
      for (int gg = 0; gg < 4; ++gg) {
        pre[gg] = bias_lds[gg][j] + g_lds[gg][am][j]
               + s0 * wih_lds[gg][j][0] + s1 * wih_lds[gg][j][1]
               + s2 * wih_lds[gg][j][2] + s3 * wih_lds[gg][j][3]
               + s4 * wih_lds[gg][j][4];
      }
      float ig = sigmoidf_fast(pre[0]);
      float fg = sigmoidf_fast(pre[1]);
      float gv = tanhf_fast(pre[2]);
      float og = sigmoidf_fast(pre[3]);
      float& c = e ? c1 : c0;
      c = fg * c + ig * gv;
      hv[e] = og * tanhf_fast(c);
    }
    // h store: device-scope write-through (one u32 = 2 bf16 per thread)
    unsigned pack = (unsigned)f2bf_rne(hv[0]) | ((unsigned)f2bf_rne(hv[1]) << 16);
    __hip_atomic_store(
        reinterpret_cast<unsigned*>(hcur + (size_t)ab * HID + ht * HB + aj),
        pack, __ATOMIC_RELAXED, __HIP_MEMORY_SCOPE_AGENT);

    // ---- group barrier (8 blocks sharing bt); flags of a group in one line
    __syncthreads();   // all waves' h stores drained before flag
    if (tid == 0) {
      __hip_atomic_store(&flags[bt * 16 + ht], t + 1, __ATOMIC_RELEASE,
                         __HIP_MEMORY_SCOPE_AGENT);
    }
    if (tid < 8) {     // 8 lanes poll 8 flags in ONE 64B line
      while (__hip_atomic_load(&flags[bt * 16 + tid], __ATOMIC_RELAXED,
                               __HIP_MEMORY_SCOPE_AGENT) < t + 1) { }
    }
    __syncthreads();
  }

  // ---- final projection: member ht==0 of each group handles its 32 rows.
  // h(249) lives in hb1 (t=249 odd); last barrier made it MALL-visible.
  if (ht == 0) {
    const char* hsrc = reinterpret_cast<const char*>(hb1 + (size_t)bt * MB * HID);
    u32x4 tmp[2];
    #pragma unroll
    for (int i = 0; i < 2; ++i) {
      mall_load_16B(tmp[i], hsrc + (size_t)(i * 1024 + tid) * 16);
    }
    vm_drain();
    #pragma unroll
    for (int i = 0; i < 2; ++i) {
      int off = i * 1024 + tid;
      int row = off >> 6;
      int c   = off & 63;
      h_lds[row * 64 + (c ^ (row & 7))] = tmp[i];
    }
    __syncthreads();
    if (tid < 32) {
      const int b = bt * MB + tid;
      float sacc = 0.f;
      for (int k = 0; k < HID; ++k) {
        int c = k >> 3;   // 16B chunk
        const unsigned short* ch = reinterpret_cast<const unsigned short*>(
            &h_lds[tid * 64 + (c ^ (tid & 7))]);
        sacc += bf2f(ch[k & 7]) * W_out[k];
      }
      float raw = sacc + b_out[0];
      float lr = raw > 0.f ? raw : 0.1f * raw;
      out[b] = 1.0f / (1.0f + __expf(-lr));
    }
  }
}

extern "C" void kernel_launch(void* const* d_in, const int* in_sizes, int n_in,
                              void* d_out, int out_size, void* d_ws, size_t ws_size,
                              hipStream_t stream) {
  const float* strokes = (const float*)d_in[0];
  const float* W_ih    = (const float*)d_in[1];
  const float* W_hh    = (const float*)d_in[2];
  const float* b_ih    = (const float*)d_in[3];
  const float* b_hh    = (const float*)d_in[4];
  const float* W_out   = (const float*)d_in[5];
  const float* b_out   = (const float*)d_in[6];
  float* out = (float*)d_out;

  char* ws = (char*)d_ws;
  unsigned short* hbuf = (unsigned short*)ws;                        // 512 KB
  int* flags = (int*)(ws + (size_t)2 * BATCH * HID * 2);             // 512 B

  lstm_persist<<<NBLK, 1024, 0, stream>>>(strokes, W_ih, W_hh, b_ih, b_hh,
                                          W_out, b_out, out, hbuf, flags);
}

// Round 7
// 1440.082 us; speedup vs baseline: 1.2274x; 1.2274x over previous
//
#include <hip/hip_runtime.h>
#include <hip/hip_bf16.h>

#define BATCH 256
#define SEQ   250
#define HID   512
#define INDIM 5

#define NBLK  256
#define MB    32   // batch rows per block (8 batch tiles = 8 barrier groups)
#define HB    16   // hidden units per block (32 hidden tiles = 32 group members)

typedef __attribute__((ext_vector_type(8))) short short8;
typedef __attribute__((ext_vector_type(4))) float f32x4;
typedef __attribute__((ext_vector_type(4))) unsigned int u32x4;

__device__ __forceinline__ float sigmoidf_fast(float x) {
  return 1.0f / (1.0f + __expf(-x));
}
__device__ __forceinline__ float tanhf_fast(float x) {
  return 2.0f / (1.0f + __expf(-2.0f * x)) - 1.0f;
}
__device__ __forceinline__ unsigned short f2bf_rne(float x) {
  union { float f; unsigned u; } v; v.f = x;
  unsigned r = v.u + 0x7fffu + ((v.u >> 16) & 1u);
  return (unsigned short)(r >> 16);
}
__device__ __forceinline__ float bf2f(unsigned short h) {
  union { unsigned u; float f; } v; v.u = ((unsigned)h) << 16;
  return v.f;
}

// R4 skeleton + XCD-local fast path with guaranteed-progress protocol:
// - one leader per group publishes a group-uniform fast/slow verdict
//   (bounded poll; timeout -> slow = R4 exactly)
// - barrier flags stored to BOTH an L2 line (sc0) and a MALL line (agent
//   atomic); pollers probe L2, periodically check MALL -> no deadlock even
//   if the sc0 visibility model is wrong
// - explicit vmcnt(0) drains before barriers (asm stores aren't tracked by
//   the compiler's barrier waitcnt)
__global__ __launch_bounds__(256, 2) void lstm_persist(
    const float* __restrict__ strokes, const float* __restrict__ W_ih,
    const float* __restrict__ W_hh, const float* __restrict__ b_ih,
    const float* __restrict__ b_hh, const float* __restrict__ W_out,
    const float* __restrict__ b_out, float* __restrict__ out,
    unsigned short* __restrict__ hbuf,   // 2 * 256 * 512 bf16 (double buffer)
    int* __restrict__ flagsML,           // 256*16 ints, MALL copy (poison < 0)
    int* __restrict__ flagsL2,           // 256*16 ints, L2 copy   (poison < 0)
    int* __restrict__ xcd_ids,           // 256 ints (poison < 0)
    int* __restrict__ vflag)             // 8*16 ints verdicts (poison < 0)
{
  const int tid  = threadIdx.x;
  const int bid  = blockIdx.x;
  const int bt   = bid & 7;      // batch tile / barrier group
  const int ht   = bid >> 3;     // hidden tile 0..31 / group member
  const int wv   = tid >> 6;     // wave id = gate type 0..3 (i,f,g,o)
  const int lane = tid & 63;
  const int n16  = lane & 15;
  const int q    = lane >> 4;

  __shared__ u32x4 h_lds[MB * 64];                // 32 KB, swizzled 16B chunks
  __shared__ float g_lds[4][MB][17];              // gate values, padded
  __shared__ float wih_lds[4][HB][INDIM];
  __shared__ float bias_lds[4][HB];
  __shared__ int fast_s;

  // ---- publish my XCC id (device scope)
  unsigned xcc;
  asm volatile("s_getreg_b32 %0, hwreg(HW_REG_XCC_ID)" : "=s"(xcc));
  xcc &= 0xfu;
  if (tid == 0) {
    __hip_atomic_store(&xcd_ids[bid], (int)xcc, __ATOMIC_RELAXED,
                       __HIP_MEMORY_SCOPE_AGENT);
  }

  // ---- leader (ht==0, i.e. bid<8) computes group-uniform verdict, BOUNDED
  if (bid < 8 && wv == 0) {
    int other = (int)xcc;
    if (lane < 32) {
      const int* xp = &xcd_ids[bid + 8 * lane];
      other = -1;
      for (int it = 0; it < 16384 && other < 0; ++it) {
        other = __hip_atomic_load(xp, __ATOMIC_RELAXED, __HIP_MEMORY_SCOPE_AGENT);
      }
    }
    unsigned long long ok = __ballot(other == (int)xcc);
    if (lane == 0) {
      __hip_atomic_store(&vflag[bid * 16], (ok == ~0ull) ? 2 : 1,
                         __ATOMIC_RELAXED, __HIP_MEMORY_SCOPE_AGENT);
    }
  }
  // ---- all blocks wait for their leader's verdict (leader is co-resident
  // and its work is bounded -> this terminates)
  if (tid == 0) {
    int v;
    do {
      v = __hip_atomic_load(&vflag[bt * 16], __ATOMIC_RELAXED,
                            __HIP_MEMORY_SCOPE_AGENT);
    } while (v <= 0);
    fast_s = (v == 2) ? 1 : 0;
  }

  // ---- preload W_ih slice + combined biases into LDS
  if (tid < 64) {
    int g = tid >> 4, j = tid & 15;
    int r = g * HID + ht * HB + j;
    #pragma unroll
    for (int i = 0; i < INDIM; ++i) wih_lds[g][j][i] = W_ih[r * INDIM + i];
    bias_lds[g][j] = b_ih[r] + b_hh[r];
  }

  // ---- preload W_hh as bf16 MFMA B-fragments (weight-stationary)
  short8 wfrag[16];
  {
    const float* wr = W_hh + (size_t)(wv * HID + ht * HB + n16) * HID;
    #pragma unroll
    for (int kb = 0; kb < 16; ++kb) {
      const float* p = wr + kb * 32 + q * 8;
      short8 f;
      #pragma unroll
      for (int j = 0; j < 8; ++j) f[j] = (short)f2bf_rne(p[j]);
      wfrag[kb] = f;
    }
  }
  __syncthreads();
  const bool fast = fast_s != 0;

  // activation-phase mapping: thread -> (batch row am, hidden pair aj)
  const int am = tid >> 3;            // 0..31
  const int aj = (tid & 7) * 2;       // 0,2,..,14
  const int ab = bt * MB + am;        // global batch row
  float c0 = 0.f, c1 = 0.f;

  unsigned short* hb0 = hbuf;
  unsigned short* hb1 = hbuf + BATCH * HID;

  for (int t = 0; t < SEQ; ++t) {
    unsigned short* hprev = (t & 1) ? hb0 : hb1;
    unsigned short* hcur  = (t & 1) ? hb1 : hb0;

    const float* sp = strokes + ((size_t)ab * SEQ + t) * INDIM;
    float s0 = sp[0], s1 = sp[1], s2 = sp[2], s3 = sp[3], s4 = sp[4];

    f32x4 acc[2][2] = {};
    if (t > 0) {
      // ---- stage h(t-1) tile (32 rows x 512 bf16 = 32 KB) into LDS.
      const char* hsrc = reinterpret_cast<const char*>(hprev + (size_t)bt * MB * HID);
      u32x4 tmp[8];
      if (fast) {
        #pragma unroll
        for (int i = 0; i < 8; ++i)
          asm volatile("global_load_dwordx4 %0, %1, off sc0"
                       : "=v"(tmp[i]) : "v"(hsrc + (size_t)(i * 256 + tid) * 16)
                       : "memory");
      } else {
        #pragma unroll
        for (int i = 0; i < 8; ++i)
          asm volatile("global_load_dwordx4 %0, %1, off sc0 sc1"
                       : "=v"(tmp[i]) : "v"(hsrc + (size_t)(i * 256 + tid) * 16)
                       : "memory");
      }
      asm volatile("s_waitcnt vmcnt(0)" ::: "memory");
      #pragma unroll
      for (int i = 0; i < 8; ++i) {
        int off = i * 256 + tid;
        int row = off >> 6;
        int c   = off & 63;
        h_lds[row * 64 + (c ^ (row & 7))] = tmp[i];
      }
      __syncthreads();

      #pragma unroll
      for (int kb = 0; kb < 16; ++kb) {
        #pragma unroll
        for (int mt = 0; mt < 2; ++mt) {
          const int row = mt * 16 + n16;
          const int c   = kb * 4 + q;                 // 16B chunk in row
          const short8 a = *reinterpret_cast<const short8*>(
              &h_lds[row * 64 + (c ^ (row & 7))]);
          acc[mt][kb & 1] = __builtin_amdgcn_mfma_f32_16x16x32_bf16(
              a, wfrag[kb], acc[mt][kb & 1], 0, 0, 0);
        }
      }
    }

    // C-layout: col = lane&15, row = q*4 + reg
    #pragma unroll
    for (int mt = 0; mt < 2; ++mt) {
      #pragma unroll
      for (int r = 0; r < 4; ++r) {
        g_lds[wv][mt * 16 + q * 4 + r][n16] = acc[mt][0][r] + acc[mt][1][r];
      }
    }
    __syncthreads();

    float hv[2];
    #pragma unroll
    for (int e = 0; e < 2; ++e) {
      int j = aj + e;
      float pre[4];
      #pragma unroll
      for (int g = 0; g < 4; ++g) {
        pre[g] = bias_lds[g][j] + g_lds[g][am][j]
               + s0 * wih_lds[g][j][0] + s1 * wih_lds[g][j][1]
               + s2 * wih_lds[g][j][2] + s3 * wih_lds[g][j][3]
               + s4 * wih_lds[g][j][4];
      }
      float ig = sigmoidf_fast(pre[0]);
      float fg = sigmoidf_fast(pre[1]);
      float gg = tanhf_fast(pre[2]);
      float og = sigmoidf_fast(pre[3]);
      float& c = e ? c1 : c0;
      c = fg * c + ig * gg;
      hv[e] = og * tanhf_fast(c);
    }
    // h store: one u32 = 2 bf16 per thread
    unsigned pack = (unsigned)f2bf_rne(hv[0]) | ((unsigned)f2bf_rne(hv[1]) << 16);
    unsigned* hp = reinterpret_cast<unsigned*>(hcur + (size_t)ab * HID + ht * HB + aj);
    if (fast) {
      asm volatile("global_store_dword %0, %1, off sc0"
                   :: "v"(hp), "v"(pack) : "memory");
    } else {
      __hip_atomic_store(hp, pack, __ATOMIC_RELAXED, __HIP_MEMORY_SCOPE_AGENT);
    }

    // ---- group barrier (32 blocks sharing bt), generation t+1.
    // Drain THIS wave's h stores to their coherence point, then barrier, so
    // the flag publisher runs only after every wave's h is visible.
    asm volatile("s_waitcnt vmcnt(0)" ::: "memory");
    __syncthreads();
    const int gen = t + 1;
    if (tid == 0) {
      if (fast) {
        asm volatile("global_store_dword %0, %1, off sc0"
                     :: "v"(&flagsL2[bid * 16]), "v"(gen) : "memory");
      }
      __hip_atomic_store(&flagsML[bid * 16], gen, __ATOMIC_RELAXED,
                         __HIP_MEMORY_SCOPE_AGENT);   // MALL copy (escape path)
    }
    if (tid < 32) {    // poller j watches member (bt, j), one 64B line each
      if (fast) {
        const int* fpL = &flagsL2[(bt + 8 * tid) * 16];
        const int* fpM = &flagsML[(bt + 8 * tid) * 16];
        int v = -1;
        for (;;) {
          #pragma unroll 1
          for (int p = 0; p < 32; ++p) {
            asm volatile("global_load_dword %0, %1, off sc0\n\t"
                         "s_waitcnt vmcnt(0)"
                         : "=v"(v) : "v"(fpL) : "memory");
            if (v >= gen) break;
          }
          if (v >= gen) break;
          v = __hip_atomic_load(fpM, __ATOMIC_RELAXED, __HIP_MEMORY_SCOPE_AGENT);
          if (v >= gen) break;
        }
      } else {
        while (__hip_atomic_load(&flagsML[(bt + 8 * tid) * 16], __ATOMIC_RELAXED,
                                 __HIP_MEMORY_SCOPE_AGENT) < gen) { }
      }
    }
    __syncthreads();
  }

  // ---- final projection: member ht==0 of each group handles its 32 rows.
  // h(249) lives in hb1 (t=249 odd); last barrier made it visible at the
  // exchange scope (L2 if fast, MALL if not) -- ht==0 is in-group.
  if (ht == 0) {
    const char* hsrc = reinterpret_cast<const char*>(hb1 + (size_t)bt * MB * HID);
    u32x4 tmp[8];
    if (fast) {
      #pragma unroll
      for (int i = 0; i < 8; ++i)
        asm volatile("global_load_dwordx4 %0, %1, off sc0"
                     : "=v"(tmp[i]) : "v"(hsrc + (size_t)(i * 256 + tid) * 16)
                     : "memory");
    } else {
      #pragma unroll
      for (int i = 0; i < 8; ++i)
        asm volatile("global_load_dwordx4 %0, %1, off sc0 sc1"
                     : "=v"(tmp[i]) : "v"(hsrc + (size_t)(i * 256 + tid) * 16)
                     : "memory");
    }
    asm volatile("s_waitcnt vmcnt(0)" ::: "memory");
    #pragma unroll
    for (int i = 0; i < 8; ++i) {
      int off = i * 256 + tid;
      int row = off >> 6;
      int c   = off & 63;
      h_lds[row * 64 + (c ^ (row & 7))] = tmp[i];
    }
    __syncthreads();
    if (tid < 32) {
      const int b = bt * MB + tid;
      float s = 0.f;
      for (int k = 0; k < HID; ++k) {
        int c = k >> 3;   // 16B chunk
        const unsigned short* ch = reinterpret_cast<const unsigned short*>(
            &h_lds[tid * 64 + (c ^ (tid & 7))]);
        s += bf2f(ch[k & 7]) * W_out[k];
      }
      float raw = s + b_out[0];
      float lr = raw > 0.f ? raw : 0.1f * raw;
      out[b] = 1.0f / (1.0f + __expf(-lr));
    }
  }
}

extern "C" void kernel_launch(void* const* d_in, const int* in_sizes, int n_in,
                              void* d_out, int out_size, void* d_ws, size_t ws_size,
                              hipStream_t stream) {
  const float* strokes = (const float*)d_in[0];
  const float* W_ih    = (const float*)d_in[1];
  const float* W_hh    = (const float*)d_in[2];
  const float* b_ih    = (const float*)d_in[3];
  const float* b_hh    = (const float*)d_in[4];
  const float* W_out   = (const float*)d_in[5];
  const float* b_out   = (const float*)d_in[6];
  float* out = (float*)d_out;

  char* ws = (char*)d_ws;
  unsigned short* hbuf = (unsigned short*)ws;                 // 512 KB
  size_t off = (size_t)2 * BATCH * HID * 2;
  int* flagsML = (int*)(ws + off);  off += 16384;             // 16 KB
  int* flagsL2 = (int*)(ws + off);  off += 16384;             // 16 KB
  int* xcd_ids = (int*)(ws + off);  off += 1024;              // 1 KB
  int* vflag   = (int*)(ws + off);                            // 512 B

  lstm_persist<<<NBLK, 256, 0, stream>>>(strokes, W_ih, W_hh, b_ih, b_hh,
                                         W_out, b_out, out, hbuf,
                                         flagsML, flagsL2, xcd_ids, vflag);
}

// Round 9
// 1064.032 us; speedup vs baseline: 1.6612x; 1.3534x over previous
//
#include <hip/hip_runtime.h>
#include <hip/hip_bf16.h>

#define BATCH 256
#define SEQ   250
#define HID   512
#define INDIM 5

#define NBLK  256
#define MB    32   // batch rows per block (8 batch tiles = 8 barrier groups)
#define HB    16   // hidden units per block (32 hidden tiles = 32 group members)

// member-major h buffers: slot s (2) | group bt (8) | member j (32) | 1KB
//   member block global: j*1024 + row*32 + col*2   (32 rows x 16 cols bf16)
// LDS copy: 48B row stride (2-way max bank aliasing = free)
#define LROW 24          // ushorts per LDS row (48B)
#define LMEM 768         // ushorts per member block (32*24)
#define SLOT_BYTES (BATCH * HID * 2)   // 256KB per slot

typedef __attribute__((ext_vector_type(8))) short short8;
typedef __attribute__((ext_vector_type(4))) float f32x4;
typedef __attribute__((ext_vector_type(4))) unsigned int u32x4;

__device__ __forceinline__ float sigmoidf_fast(float x) {
  return 1.0f / (1.0f + __expf(-x));
}
__device__ __forceinline__ float tanhf_fast(float x) {
  return 2.0f / (1.0f + __expf(-2.0f * x)) - 1.0f;
}
__device__ __forceinline__ unsigned short f2bf_rne(float x) {
  union { float f; unsigned u; } v; v.f = x;
  unsigned r = v.u + 0x7fffu + ((v.u >> 16) & 1u);
  return (unsigned short)(r >> 16);
}
__device__ __forceinline__ float bf2f(unsigned short h) {
  union { unsigned u; float f; } v; v.u = ((unsigned)h) << 16;
  return v.f;
}

// R9 = R8's pipelined poll+stage + R7's guaranteed-progress polling.
// Publisher writes gen to BOTH an L2 line (sc0) and a MALL line (agent
// atomic). Pollers probe L2 16x, then check MALL once, repeat -> no
// deadlock even if sc0 visibility ever fails (R6/R8, which polled L2 only,
// died; R7 with the escape passed). Wave w owns members w*8..w*8+7: its
// lanes 0..7 spin on those flags, then the wave immediately stages their
// 8x1KB into LDS -- staging of early members overlaps waiting on stragglers.
__global__ __launch_bounds__(256, 2) void lstm_persist(
    const float* __restrict__ strokes, const float* __restrict__ W_ih,
    const float* __restrict__ W_hh, const float* __restrict__ b_ih,
    const float* __restrict__ b_hh, const float* __restrict__ W_out,
    const float* __restrict__ b_out, float* __restrict__ out,
    unsigned short* __restrict__ hbuf,   // 2 slots * 256KB, member-major
    int* __restrict__ flagsML,           // 256*16 ints, MALL copy (poison < 0)
    int* __restrict__ flagsL2,           // 256*16 ints, L2 copy   (poison < 0)
    int* __restrict__ xcd_ids,           // 256 ints (poison < 0)
    int* __restrict__ vflag)             // 8*16 ints verdicts (poison < 0)
{
  const int tid  = threadIdx.x;
  const int bid  = blockIdx.x;
  const int bt   = bid & 7;      // batch tile / barrier group
  const int ht   = bid >> 3;     // hidden tile 0..31 / group member
  const int wv   = tid >> 6;     // wave id = gate type 0..3 (i,f,g,o)
  const int lane = tid & 63;
  const int n16  = lane & 15;
  const int q    = lane >> 4;

  __shared__ unsigned short h_lds[32 * LMEM];     // 48KB member-major h tile
  __shared__ float g_lds[4][MB][17];              // gate values, padded
  __shared__ float wih_lds[4][HB][INDIM];
  __shared__ float bias_lds[4][HB];
  __shared__ int fast_s;

  // ---- publish my XCC id (device scope)
  unsigned xcc;
  asm volatile("s_getreg_b32 %0, hwreg(HW_REG_XCC_ID)" : "=s"(xcc));
  xcc &= 0xfu;
  if (tid == 0) {
    __hip_atomic_store(&xcd_ids[bid], (int)xcc, __ATOMIC_RELAXED,
                       __HIP_MEMORY_SCOPE_AGENT);
  }
  // ---- leader (bid<8) computes group-uniform verdict, BOUNDED poll
  if (bid < 8 && wv == 0) {
    int other = (int)xcc;
    if (lane < 32) {
      const int* xp = &xcd_ids[bid + 8 * lane];
      other = -1;
      for (int it = 0; it < 16384 && other < 0; ++it) {
        other = __hip_atomic_load(xp, __ATOMIC_RELAXED, __HIP_MEMORY_SCOPE_AGENT);
      }
    }
    unsigned long long ok = __ballot(other == (int)xcc);
    if (lane == 0) {
      __hip_atomic_store(&vflag[bid * 16], (ok == ~0ull) ? 2 : 1,
                         __ATOMIC_RELAXED, __HIP_MEMORY_SCOPE_AGENT);
    }
  }
  if (tid == 0) {   // wait leader (co-resident, bounded work -> terminates)
    int v;
    do {
      v = __hip_atomic_load(&vflag[bt * 16], __ATOMIC_RELAXED,
                            __HIP_MEMORY_SCOPE_AGENT);
    } while (v <= 0);
    fast_s = (v == 2) ? 1 : 0;
  }

  // ---- preload W_ih slice + combined biases into LDS
  if (tid < 64) {
    int g = tid >> 4, j = tid & 15;
    int r = g * HID + ht * HB + j;
    #pragma unroll
    for (int i = 0; i < INDIM; ++i) wih_lds[g][j][i] = W_ih[r * INDIM + i];
    bias_lds[g][j] = b_ih[r] + b_hh[r];
  }

  // ---- preload W_hh as bf16 MFMA B-fragments (weight-stationary)
  short8 wfrag[16];
  {
    const float* wr = W_hh + (size_t)(wv * HID + ht * HB + n16) * HID;
    #pragma unroll
    for (int kb = 0; kb < 16; ++kb) {
      const float* p = wr + kb * 32 + q * 8;
      short8 f;
      #pragma unroll
      for (int j = 0; j < 8; ++j) f[j] = (short)f2bf_rne(p[j]);
      wfrag[kb] = f;
    }
  }
  __syncthreads();
  const bool fast = fast_s != 0;

  // activation-phase mapping: thread -> (batch row am, hidden pair aj)
  const int am = tid >> 3;            // 0..31
  const int aj = (tid & 7) * 2;       // 0,2,..,14
  const int ab = bt * MB + am;        // global batch row
  const int j0 = wv * 8;              // this wave's first member
  float c0 = 0.f, c1 = 0.f;

  for (int t = 0; t < SEQ; ++t) {
    unsigned short* hprev = hbuf + (((t & 1) ^ 1) ? (SLOT_BYTES / 2) : 0);
    unsigned short* hcur  = hbuf + ((t & 1) ? (SLOT_BYTES / 2) : 0);

    const float* sp = strokes + ((size_t)ab * SEQ + t) * INDIM;
    float s0 = sp[0], s1 = sp[1], s2 = sp[2], s3 = sp[3], s4 = sp[4];

    f32x4 acc[2][2] = {};
    if (t > 0) {
      // ---- pipelined poll+stage with MALL escape
      if (lane < 8) {
        const int* fpL = &flagsL2[(bt + 8 * (j0 + lane)) * 16];
        const int* fpM = &flagsML[(bt + 8 * (j0 + lane)) * 16];
        if (fast) {
          int v = -1;
          while (v < t) {
            #pragma unroll 1
            for (int p = 0; p < 16 && v < t; ++p) {
              asm volatile("global_load_dword %0, %1, off sc0\n\t"
                           "s_waitcnt vmcnt(0)"
                           : "=v"(v) : "v"(fpL) : "memory");
            }
            if (v < t) {
              v = __hip_atomic_load(fpM, __ATOMIC_RELAXED,
                                    __HIP_MEMORY_SCOPE_AGENT);
            }
          }
        } else {
          while (__hip_atomic_load(fpM, __ATOMIC_RELAXED,
                                   __HIP_MEMORY_SCOPE_AGENT) < t) { }
        }
      }
      const char* base = reinterpret_cast<const char*>(hprev) + bt * 32768;
      u32x4 tmp[8];
      if (fast) {
        #pragma unroll
        for (int m = 0; m < 8; ++m)
          asm volatile("global_load_dwordx4 %0, %1, off sc0"
                       : "=v"(tmp[m])
                       : "v"(base + (j0 + m) * 1024 + lane * 16) : "memory");
      } else {
        #pragma unroll
        for (int m = 0; m < 8; ++m)
          asm volatile("global_load_dwordx4 %0, %1, off sc0 sc1"
                       : "=v"(tmp[m])
                       : "v"(base + (j0 + m) * 1024 + lane * 16) : "memory");
      }
      asm volatile("s_waitcnt vmcnt(0)" ::: "memory");
      #pragma unroll
      for (int m = 0; m < 8; ++m) {
        // bytes lane*16 of member block -> row = lane>>1, half = lane&1
        *reinterpret_cast<u32x4*>(
            &h_lds[(j0 + m) * LMEM + (lane >> 1) * LROW + (lane & 1) * 8]) = tmp[m];
      }
      __syncthreads();

      #pragma unroll
      for (int kb = 0; kb < 16; ++kb) {
        const int jm   = kb * 2 + (q >> 1);        // member holding k-range
        const int koff = jm * LMEM + (q & 1) * 8;  // + row*LROW below
        #pragma unroll
        for (int mt = 0; mt < 2; ++mt) {
          const int row = mt * 16 + n16;
          const short8 a = *reinterpret_cast<const short8*>(
              &h_lds[koff + row * LROW]);
          acc[mt][kb & 1] = __builtin_amdgcn_mfma_f32_16x16x32_bf16(
              a, wfrag[kb], acc[mt][kb & 1], 0, 0, 0);
        }
      }
    }

    // C-layout: col = lane&15, row = q*4 + reg
    #pragma unroll
    for (int mt = 0; mt < 2; ++mt) {
      #pragma unroll
      for (int r = 0; r < 4; ++r) {
        g_lds[wv][mt * 16 + q * 4 + r][n16] = acc[mt][0][r] + acc[mt][1][r];
      }
    }
    __syncthreads();

    float hv[2];
    #pragma unroll
    for (int e = 0; e < 2; ++e) {
      int j = aj + e;
      float pre[4];
      #pragma unroll
      for (int g = 0; g < 4; ++g) {
        pre[g] = bias_lds[g][j] + g_lds[g][am][j]
               + s0 * wih_lds[g][j][0] + s1 * wih_lds[g][j][1]
               + s2 * wih_lds[g][j][2] + s3 * wih_lds[g][j][3]
               + s4 * wih_lds[g][j][4];
      }
      float ig = sigmoidf_fast(pre[0]);
      float fg = sigmoidf_fast(pre[1]);
      float gg = tanhf_fast(pre[2]);
      float og = sigmoidf_fast(pre[3]);
      float& c = e ? c1 : c0;
      c = fg * c + ig * gg;
      hv[e] = og * tanhf_fast(c);
    }
    // h store, member-major: member ht's 1KB at bt*32KB + ht*1KB
    unsigned pack = (unsigned)f2bf_rne(hv[0]) | ((unsigned)f2bf_rne(hv[1]) << 16);
    unsigned* hp = reinterpret_cast<unsigned*>(
        reinterpret_cast<char*>(hcur) + bt * 32768 + ht * 1024 + am * 32 + aj * 2);
    if (fast) {
      asm volatile("global_store_dword %0, %1, off sc0"
                   :: "v"(hp), "v"(pack) : "memory");
    } else {
      __hip_atomic_store(hp, pack, __ATOMIC_RELAXED, __HIP_MEMORY_SCOPE_AGENT);
    }

    // ---- publish gen = t+1 after ALL waves' h stores are drained
    asm volatile("s_waitcnt vmcnt(0)" ::: "memory");
    __syncthreads();
    const int gen = t + 1;
    if (tid == 0) {
      if (fast) {
        asm volatile("global_store_dword %0, %1, off sc0"
                     :: "v"(&flagsL2[bid * 16]), "v"(gen) : "memory");
      }
      __hip_atomic_store(&flagsML[bid * 16], gen, __ATOMIC_RELAXED,
                         __HIP_MEMORY_SCOPE_AGENT);   // MALL copy (escape path)
    }
    // next iteration's poll (or the final-proj poll) is the consumer wait
  }

  // ---- final projection: member ht==0 of each group, 32 rows.
  if (ht == 0) {
    if (lane < 8) {
      const int* fpL = &flagsL2[(bt + 8 * (j0 + lane)) * 16];
      const int* fpM = &flagsML[(bt + 8 * (j0 + lane)) * 16];
      if (fast) {
        int v = -1;
        while (v < SEQ) {
          #pragma unroll 1
          for (int p = 0; p < 16 && v < SEQ; ++p) {
            asm volatile("global_load_dword %0, %1, off sc0\n\t"
                         "s_waitcnt vmcnt(0)"
                         : "=v"(v) : "v"(fpL) : "memory");
          }
          if (v < SEQ) {
            v = __hip_atomic_load(fpM, __ATOMIC_RELAXED,
                                  __HIP_MEMORY_SCOPE_AGENT);
          }
        }
      } else {
        while (__hip_atomic_load(fpM, __ATOMIC_RELAXED,
                                 __HIP_MEMORY_SCOPE_AGENT) < SEQ) { }
      }
    }
    const char* base = reinterpret_cast<const char*>(hbuf)
                     + ((SEQ - 1) & 1) * SLOT_BYTES + bt * 32768;
    u32x4 tmp[8];
    if (fast) {
      #pragma unroll
      for (int m = 0; m < 8; ++m)
        asm volatile("global_load_dwordx4 %0, %1, off sc0"
                     : "=v"(tmp[m])
                     : "v"(base + (j0 + m) * 1024 + lane * 16) : "memory");
    } else {
      #pragma unroll
      for (int m = 0; m < 8; ++m)
        asm volatile("global_load_dwordx4 %0, %1, off sc0 sc1"
                     : "=v"(tmp[m])
                     : "v"(base + (j0 + m) * 1024 + lane * 16) : "memory");
    }
    asm volatile("s_waitcnt vmcnt(0)" ::: "memory");
    #pragma unroll
    for (int m = 0; m < 8; ++m) {
      *reinterpret_cast<u32x4*>(
          &h_lds[(j0 + m) * LMEM + (lane >> 1) * LROW + (lane & 1) * 8]) = tmp[m];
    }
    __syncthreads();
    if (tid < 32) {
      const int b = bt * MB + tid;
      float s = 0.f;
      for (int k = 0; k < HID; ++k) {
        s += bf2f(h_lds[(k >> 4) * LMEM + tid * LROW + (k & 15)]) * W_out[k];
      }
      float raw = s + b_out[0];
      float lr = raw > 0.f ? raw : 0.1f * raw;
      out[b] = 1.0f / (1.0f + __expf(-lr));
    }
  }
}

extern "C" void kernel_launch(void* const* d_in, const int* in_sizes, int n_in,
                              void* d_out, int out_size, void* d_ws, size_t ws_size,
                              hipStream_t stream) {
  const float* strokes = (const float*)d_in[0];
  const float* W_ih    = (const float*)d_in[1];
  const float* W_hh    = (const float*)d_in[2];
  const float* b_ih    = (const float*)d_in[3];
  const float* b_hh    = (const float*)d_in[4];
  const float* W_out   = (const float*)d_in[5];
  const float* b_out   = (const float*)d_in[6];
  float* out = (float*)d_out;

  char* ws = (char*)d_ws;
  unsigned short* hbuf = (unsigned short*)ws;                 // 512 KB (2 slots)
  size_t off = (size_t)2 * SLOT_BYTES;
  int* flagsML = (int*)(ws + off);  off += 16384;             // 16 KB
  int* flagsL2 = (int*)(ws + off);  off += 16384;             // 16 KB
  int* xcd_ids = (int*)(ws + off);  off += 1024;              // 1 KB
  int* vflag   = (int*)(ws + off);                            // 512 B

  lstm_persist<<<NBLK, 256, 0, stream>>>(strokes, W_ih, W_hh, b_ih, b_hh,
                                         W_out, b_out, out, hbuf,
                                         flagsML, flagsL2, xcd_ids, vflag);
}

// Round 10
// 1020.530 us; speedup vs baseline: 1.7320x; 1.0426x over previous
//
#include <hip/hip_runtime.h>
#include <hip/hip_bf16.h>

#define BATCH 256
#define SEQ   250
#define HID   512
#define INDIM 5

#define NBLK  256
#define MB    32   // batch rows per block (8 batch tiles = 8 barrier groups)
#define HB    16   // hidden units per block (32 hidden tiles = 32 group members)

// member-major h buffers: slot s (2) | group bt (8) | member j (32) | 1KB
//   member block global: j*1024 + row*32 + col*2   (32 rows x 16 cols bf16)
// LDS copy: 48B row stride (conflict-free b128 fragment reads)
#define LROW 24          // ushorts per LDS row (48B)
#define LMEM 768         // ushorts per member block (32*24)
#define SLOT_BYTES (BATCH * HID * 2)   // 256KB per slot

typedef __attribute__((ext_vector_type(8))) short short8;
typedef __attribute__((ext_vector_type(4))) float f32x4;
typedef __attribute__((ext_vector_type(4))) unsigned int u32x4;

__device__ __forceinline__ float sigmoidf_fast(float x) {
  return 1.0f / (1.0f + __expf(-x));
}
__device__ __forceinline__ float tanhf_fast(float x) {
  return 2.0f / (1.0f + __expf(-2.0f * x)) - 1.0f;
}
__device__ __forceinline__ unsigned short f2bf_rne(float x) {
  union { float f; unsigned u; } v; v.f = x;
  unsigned r = v.u + 0x7fffu + ((v.u >> 16) & 1u);
  return (unsigned short)(r >> 16);
}
__device__ __forceinline__ float bf2f(unsigned short h) {
  union { unsigned u; float f; } v; v.u = ((unsigned)h) << 16;
  return v.f;
}

// R10 = R9 + per-(member,wave) flags. Each wave publishes immediately after
// its OWN vmcnt(0) h-store drain -> sync#3 and the slowest-wave publish
// straggle are gone (2 syncs/step). Consumers poll 8 members x 4 wave-flags
// (lanes 0..31, one 64B line per member). Safety: flag(m,u)>=t implies ALL
// waves of block m passed sync#1 of step t-1 (finished reading h(t-2)), so
// slot overwrite stays race-free; block-level sync#1/#2 re-aggregate the 4
// waves' partial waits into a full 32-member wait. Dual-publish (L2 + MALL
// escape) kept from R7/R9 -- deadlock-free under any visibility model.
// wfrag[i] holds kb=(wv*4+i)&15 so the wave's OWN-staged 4 kb are MFMA'd
// before sync#1 (overlaps other waves' staging), with constant reg indices.
__global__ __launch_bounds__(256, 2) void lstm_persist(
    const float* __restrict__ strokes, const float* __restrict__ W_ih,
    const float* __restrict__ W_hh, const float* __restrict__ b_ih,
    const float* __restrict__ b_hh, const float* __restrict__ W_out,
    const float* __restrict__ b_out, float* __restrict__ out,
    unsigned short* __restrict__ hbuf,   // 2 slots * 256KB, member-major
    int* __restrict__ flagsML,           // 8*32*16 ints, MALL copy (poison<0)
    int* __restrict__ flagsL2,           // 8*32*16 ints, L2 copy   (poison<0)
    int* __restrict__ xcd_ids,           // 256 ints (poison < 0)
    int* __restrict__ vflag)             // 8*16 ints verdicts (poison < 0)
{
  const int tid  = threadIdx.x;
  const int bid  = blockIdx.x;
  const int bt   = bid & 7;      // batch tile / barrier group
  const int ht   = bid >> 3;     // hidden tile 0..31 / group member
  const int wv   = tid >> 6;     // wave id = gate type 0..3 (i,f,g,o)
  const int lane = tid & 63;
  const int n16  = lane & 15;
  const int q    = lane >> 4;

  __shared__ unsigned short h_lds[32 * LMEM];     // 48KB member-major h tile
  __shared__ float g_lds[4][MB][17];              // gate values, padded
  __shared__ float wih_lds[4][HB][INDIM];
  __shared__ float bias_lds[4][HB];
  __shared__ int fast_s;

  // ---- publish my XCC id (device scope)
  unsigned xcc;
  asm volatile("s_getreg_b32 %0, hwreg(HW_REG_XCC_ID)" : "=s"(xcc));
  xcc &= 0xfu;
  if (tid == 0) {
    __hip_atomic_store(&xcd_ids[bid], (int)xcc, __ATOMIC_RELAXED,
                       __HIP_MEMORY_SCOPE_AGENT);
  }
  // ---- leader (bid<8) computes group-uniform verdict, BOUNDED poll
  if (bid < 8 && wv == 0) {
    int other = (int)xcc;
    if (lane < 32) {
      const int* xp = &xcd_ids[bid + 8 * lane];
      other = -1;
      for (int it = 0; it < 16384 && other < 0; ++it) {
        other = __hip_atomic_load(xp, __ATOMIC_RELAXED, __HIP_MEMORY_SCOPE_AGENT);
      }
    }
    unsigned long long ok = __ballot(other == (int)xcc);
    if (lane == 0) {
      __hip_atomic_store(&vflag[bid * 16], (ok == ~0ull) ? 2 : 1,
                         __ATOMIC_RELAXED, __HIP_MEMORY_SCOPE_AGENT);
    }
  }
  if (tid == 0) {   // wait leader (co-resident, bounded work -> terminates)
    int v;
    do {
      v = __hip_atomic_load(&vflag[bt * 16], __ATOMIC_RELAXED,
                            __HIP_MEMORY_SCOPE_AGENT);
    } while (v <= 0);
    fast_s = (v == 2) ? 1 : 0;
  }

  // ---- preload W_ih slice + combined biases into LDS
  if (tid < 64) {
    int g = tid >> 4, j = tid & 15;
    int r = g * HID + ht * HB + j;
    #pragma unroll
    for (int i = 0; i < INDIM; ++i) wih_lds[g][j][i] = W_ih[r * INDIM + i];
    bias_lds[g][j] = b_ih[r] + b_hh[r];
  }

  // ---- preload W_hh as bf16 MFMA B-fragments, rotated: wfrag[i] <-> kb=(wv*4+i)&15
  short8 wfrag[16];
  {
    const float* wr = W_hh + (size_t)(wv * HID + ht * HB + n16) * HID;
    #pragma unroll
    for (int i = 0; i < 16; ++i) {
      const int kb = (wv * 4 + i) & 15;
      const float* p = wr + kb * 32 + q * 8;
      short8 f;
      #pragma unroll
      for (int j = 0; j < 8; ++j) f[j] = (short)f2bf_rne(p[j]);
      wfrag[i] = f;
    }
  }
  __syncthreads();
  const bool fast = fast_s != 0;

  // activation-phase mapping: thread -> (batch row am, hidden pair aj)
  const int am = tid >> 3;            // 0..31
  const int aj = (tid & 7) * 2;       // 0,2,..,14
  const int ab = bt * MB + am;        // global batch row
  const int j0 = wv * 8;              // this wave's first member
  float c0 = 0.f, c1 = 0.f;

  for (int t = 0; t < SEQ; ++t) {
    unsigned short* hprev = hbuf + (((t & 1) ^ 1) ? (SLOT_BYTES / 2) : 0);
    unsigned short* hcur  = hbuf + ((t & 1) ? (SLOT_BYTES / 2) : 0);

    const float* sp = strokes + ((size_t)ab * SEQ + t) * INDIM;
    float s0 = sp[0], s1 = sp[1], s2 = sp[2], s3 = sp[3], s4 = sp[4];

    f32x4 acc[2][2] = {};
    if (t > 0) {
      // ---- poll 8 members x 4 wave-flags (lanes 0..31), with MALL escape
      if (lane < 32) {
        const int fi = (bt * 32 + (j0 + (lane >> 2))) * 16 + (lane & 3) * 4;
        const int* fpL = &flagsL2[fi];
        const int* fpM = &flagsML[fi];
        if (fast) {
          int v = -1;
          while (v < t) {
            #pragma unroll 1
            for (int p = 0; p < 16 && v < t; ++p) {
              asm volatile("global_load_dword %0, %1, off sc0\n\t"
                           "s_waitcnt vmcnt(0)"
                           : "=v"(v) : "v"(fpL) : "memory");
            }
            if (v < t) {
              v = __hip_atomic_load(fpM, __ATOMIC_RELAXED,
                                    __HIP_MEMORY_SCOPE_AGENT);
            }
          }
        } else {
          while (__hip_atomic_load(fpM, __ATOMIC_RELAXED,
                                   __HIP_MEMORY_SCOPE_AGENT) < t) { }
        }
      }
      // ---- stage this wave's 8 members (8 x 1KB) into LDS
      const char* base = reinterpret_cast<const char*>(hprev) + bt * 32768;
      u32x4 tmp[8];
      if (fast) {
        #pragma unroll
        for (int m = 0; m < 8; ++m)
          asm volatile("global_load_dwordx4 %0, %1, off sc0"
                       : "=v"(tmp[m])
                       : "v"(base + (j0 + m) * 1024 + lane * 16) : "memory");
      } else {
        #pragma unroll
        for (int m = 0; m < 8; ++m)
          asm volatile("global_load_dwordx4 %0, %1, off sc0 sc1"
                       : "=v"(tmp[m])
                       : "v"(base + (j0 + m) * 1024 + lane * 16) : "memory");
      }
      asm volatile("s_waitcnt vmcnt(0)" ::: "memory");
      #pragma unroll
      for (int m = 0; m < 8; ++m) {
        // bytes lane*16 of member block -> row = lane>>1, half = lane&1
        *reinterpret_cast<u32x4*>(
            &h_lds[(j0 + m) * LMEM + (lane >> 1) * LROW + (lane & 1) * 8]) = tmp[m];
      }

      // ---- early MFMA: the 4 kb this wave itself staged (i = 0..3)
      #pragma unroll
      for (int i = 0; i < 4; ++i) {
        const int kb   = wv * 4 + i;               // own range, <16
        const int jm   = kb * 2 + (q >> 1);
        const int koff = jm * LMEM + (q & 1) * 8;
        #pragma unroll
        for (int mt = 0; mt < 2; ++mt) {
          const int row = mt * 16 + n16;
          const short8 a = *reinterpret_cast<const short8*>(
              &h_lds[koff + row * LROW]);
          acc[mt][i & 1] = __builtin_amdgcn_mfma_f32_16x16x32_bf16(
              a, wfrag[i], acc[mt][i & 1], 0, 0, 0);
        }
      }
      __syncthreads();   // sync#1: all waves' staging visible
      #pragma unroll
      for (int i = 4; i < 16; ++i) {
        const int kb   = (wv * 4 + i) & 15;
        const int jm   = kb * 2 + (q >> 1);
        const int koff = jm * LMEM + (q & 1) * 8;
        #pragma unroll
        for (int mt = 0; mt < 2; ++mt) {
          const int row = mt * 16 + n16;
          const short8 a = *reinterpret_cast<const short8*>(
              &h_lds[koff + row * LROW]);
          acc[mt][i & 1] = __builtin_amdgcn_mfma_f32_16x16x32_bf16(
              a, wfrag[i], acc[mt][i & 1], 0, 0, 0);
        }
      }
    }

    // C-layout: col = lane&15, row = q*4 + reg
    #pragma unroll
    for (int mt = 0; mt < 2; ++mt) {
      #pragma unroll
      for (int r = 0; r < 4; ++r) {
        g_lds[wv][mt * 16 + q * 4 + r][n16] = acc[mt][0][r] + acc[mt][1][r];
      }
    }
    __syncthreads();   // sync#2: gates visible to all waves

    float hv[2];
    #pragma unroll
    for (int e = 0; e < 2; ++e) {
      int j = aj + e;
      float pre[4];
      #pragma unroll
      for (int g = 0; g < 4; ++g) {
        pre[g] = bias_lds[g][j] + g_lds[g][am][j]
               + s0 * wih_lds[g][j][0] + s1 * wih_lds[g][j][1]
               + s2 * wih_lds[g][j][2] + s3 * wih_lds[g][j][3]
               + s4 * wih_lds[g][j][4];
      }
      float ig = sigmoidf_fast(pre[0]);
      float fg = sigmoidf_fast(pre[1]);
      float gg = tanhf_fast(pre[2]);
      float og = sigmoidf_fast(pre[3]);
      float& c = e ? c1 : c0;
      c = fg * c + ig * gg;
      hv[e] = og * tanhf_fast(c);
    }
    // h store, member-major: wave wv writes rows am in [wv*8, wv*8+8)
    unsigned pack = (unsigned)f2bf_rne(hv[0]) | ((unsigned)f2bf_rne(hv[1]) << 16);
    unsigned* hp = reinterpret_cast<unsigned*>(
        reinterpret_cast<char*>(hcur) + bt * 32768 + ht * 1024 + am * 32 + aj * 2);
    if (fast) {
      asm volatile("global_store_dword %0, %1, off sc0"
                   :: "v"(hp), "v"(pack) : "memory");
    } else {
      __hip_atomic_store(hp, pack, __ATOMIC_RELAXED, __HIP_MEMORY_SCOPE_AGENT);
    }

    // ---- per-wave publish: drain OWN wave's h stores, then flag (no sync#3)
    asm volatile("s_waitcnt vmcnt(0)" ::: "memory");
    const int gen = t + 1;
    if (lane == 0) {
      const int fi = (bt * 32 + ht) * 16 + wv * 4;
      if (fast) {
        asm volatile("global_store_dword %0, %1, off sc0"
                     :: "v"(&flagsL2[fi]), "v"(gen) : "memory");
      }
      __hip_atomic_store(&flagsML[fi], gen, __ATOMIC_RELAXED,
                         __HIP_MEMORY_SCOPE_AGENT);   // MALL escape copy
    }
    // next iteration's poll (or the final-proj poll) is the consumer wait
  }

  // ---- final projection: member ht==0 of each group, 32 rows.
  if (ht == 0) {
    if (lane < 32) {
      const int fi = (bt * 32 + (j0 + (lane >> 2))) * 16 + (lane & 3) * 4;
      const int* fpL = &flagsL2[fi];
      const int* fpM = &flagsML[fi];
      if (fast) {
        int v = -1;
        while (v < SEQ) {
          #pragma unroll 1
          for (int p = 0; p < 16 && v < SEQ; ++p) {
            asm volatile("global_load_dword %0, %1, off sc0\n\t"
                         "s_waitcnt vmcnt(0)"
                         : "=v"(v) : "v"(fpL) : "memory");
          }
          if (v < SEQ) {
            v = __hip_atomic_load(fpM, __ATOMIC_RELAXED,
                                  __HIP_MEMORY_SCOPE_AGENT);
          }
        }
      } else {
        while (__hip_atomic_load(fpM, __ATOMIC_RELAXED,
                                 __HIP_MEMORY_SCOPE_AGENT) < SEQ) { }
      }
    }
    const char* base = reinterpret_cast<const char*>(hbuf)
                     + ((SEQ - 1) & 1) * SLOT_BYTES + bt * 32768;
    u32x4 tmp[8];
    if (fast) {
      #pragma unroll
      for (int m = 0; m < 8; ++m)
        asm volatile("global_load_dwordx4 %0, %1, off sc0"
                     : "=v"(tmp[m])
                     : "v"(base + (j0 + m) * 1024 + lane * 16) : "memory");
    } else {
      #pragma unroll
      for (int m = 0; m < 8; ++m)
        asm volatile("global_load_dwordx4 %0, %1, off sc0 sc1"
                     : "=v"(tmp[m])
                     : "v"(base + (j0 + m) * 1024 + lane * 16) : "memory");
    }
    asm volatile("s_waitcnt vmcnt(0)" ::: "memory");
    #pragma unroll
    for (int m = 0; m < 8; ++m) {
      *reinterpret_cast<u32x4*>(
          &h_lds[(j0 + m) * LMEM + (lane >> 1) * LROW + (lane & 1) * 8]) = tmp[m];
    }
    __syncthreads();
    if (tid < 32) {
      const int b = bt * MB + tid;
      float s = 0.f;
      for (int k = 0; k < HID; ++k) {
        s += bf2f(h_lds[(k >> 4) * LMEM + tid * LROW + (k & 15)]) * W_out[k];
      }
      float raw = s + b_out[0];
      float lr = raw > 0.f ? raw : 0.1f * raw;
      out[b] = 1.0f / (1.0f + __expf(-lr));
    }
  }
}

extern "C" void kernel_launch(void* const* d_in, const int* in_sizes, int n_in,
                              void* d_out, int out_size, void* d_ws, size_t ws_size,
                              hipStream_t stream) {
  const float* strokes = (const float*)d_in[0];
  const float* W_ih    = (const float*)d_in[1];
  const float* W_hh    = (const float*)d_in[2];
  const float* b_ih    = (const float*)d_in[3];
  const float* b_hh    = (const float*)d_in[4];
  const float* W_out   = (const float*)d_in[5];
  const float* b_out   = (const float*)d_in[6];
  float* out = (float*)d_out;

  char* ws = (char*)d_ws;
  unsigned short* hbuf = (unsigned short*)ws;                 // 512 KB (2 slots)
  size_t off = (size_t)2 * SLOT_BYTES;
  int* flagsML = (int*)(ws + off);  off += 16384;             // 16 KB
  int* flagsL2 = (int*)(ws + off);  off += 16384;             // 16 KB
  int* xcd_ids = (int*)(ws + off);  off += 1024;              // 1 KB
  int* vflag   = (int*)(ws + off);                            // 512 B

  lstm_persist<<<NBLK, 256, 0, stream>>>(strokes, W_ih, W_hh, b_ih, b_hh,
                                         W_out, b_out, out, hbuf,
                                         flagsML, flagsL2, xcd_ids, vflag);
}